// Round 1
// baseline (11787.978 us; speedup 1.0000x reference)
//
#include <hip/hip_runtime.h>
#include <hip/hip_bf16.h>

typedef __attribute__((ext_vector_type(8))) short short8;
typedef __attribute__((ext_vector_type(4))) float floatx4;

#define Bb 32
#define Ss 2048
#define Ii 256
#define Hh 256
#define NWG 8

// ws layout: [0, 1024) flags (8 x u32, each padded to 128B); [1024, 1024+32768) h ring bf16 [2][32][256]

__device__ __forceinline__ unsigned short f2bf(float f) {
    unsigned int u = __float_as_uint(f);
    u += 0x7fffu + ((u >> 16) & 1u);   // RNE
    return (unsigned short)(u >> 16);
}

__device__ __forceinline__ float fast_sigmoid(float x) { return 1.0f / (1.0f + __expf(-x)); }
__device__ __forceinline__ float fast_tanh(float x)    { return 1.0f - 2.0f / (__expf(2.0f * x) + 1.0f); }

__global__ __launch_bounds__(256, 1)
void lstm_persistent(const float* __restrict__ x,
                     const float* __restrict__ h0,
                     const float* __restrict__ c0,
                     const float* __restrict__ Wf, const float* __restrict__ bfp,
                     const float* __restrict__ Wi, const float* __restrict__ bip,
                     const float* __restrict__ Wc, const float* __restrict__ bcp,
                     const float* __restrict__ Wo, const float* __restrict__ bop,
                     float* __restrict__ out,
                     unsigned int* __restrict__ flags,
                     unsigned short* __restrict__ ring)
{
    const int wg   = blockIdx.x;        // 0..7, owns h-cols [wg*32, wg*32+32)
    const int tid  = threadIdx.x;
    const int wave = tid >> 6;          // 0..3
    const int lane = tid & 63;
    const int mtile = wave & 1;         // batch half
    const int chalf = wave >> 1;        // col half
    const int ln = lane & 15;           // A-row (batch within mtile) / B,D col
    const int lg = lane >> 4;           // k lane-group 0..3
    const int j0 = wg * 32 + chalf * 16; // h-col base for this wave
    const int r0 = mtile * 16;           // batch base for this wave

    const float* Wg[4] = {Wf, Wi, Wc, Wo};
    const float* bg[4] = {bfp, bip, bcp, bop};

    // ---- one-time: weights -> registers (bf16 B-fragments), k = 32*ks + 8*lg + i
    short8 Bfrag[4][16];
#pragma unroll
    for (int g = 0; g < 4; ++g) {
#pragma unroll
        for (int ks = 0; ks < 16; ++ks) {
            short8 v;
#pragma unroll
            for (int i = 0; i < 8; ++i) {
                int k = 32 * ks + 8 * lg + i;
                v[i] = (short)f2bf(Wg[g][k * Hh + (j0 + ln)]);
            }
            Bfrag[g][ks] = v;
        }
    }

    float bias[4];
#pragma unroll
    for (int g = 0; g < 4; ++g) bias[g] = bg[g][j0 + ln];

    // c state lives in registers for the whole sequence (C/D layout: row=4*lg+r, col=ln)
    float cst[4], hl[4];
#pragma unroll
    for (int r = 0; r < 4; ++r) {
        cst[r] = c0[(r0 + 4 * lg + r) * Hh + (j0 + ln)];
        hl[r] = 0.0f;
    }

    // ---- publish h0 slice (this wg's 32 cols, all 32 rows) into ring slot 0
    {
        int row = tid >> 3;                 // 0..31
        int jj  = wg * 32 + (tid & 7) * 4;  // 4 consecutive cols
        unsigned long long pk = 0;
#pragma unroll
        for (int q = 0; q < 4; ++q)
            pk |= (unsigned long long)f2bf(h0[row * Hh + jj + q]) << (16 * q);
        __hip_atomic_store((unsigned long long*)(ring + row * Hh + jj), pk,
                           __ATOMIC_RELAXED, __HIP_MEMORY_SCOPE_AGENT);
    }
    __syncthreads();   // drains vmcnt: ring stores complete before flag
    if (tid == 0)
        __hip_atomic_store(flags + wg * 32, 1u, __ATOMIC_RELEASE, __HIP_MEMORY_SCOPE_AGENT);

    unsigned int* myflag = flags + (lane & 7) * 32;
    int outbase[4];
#pragma unroll
    for (int r = 0; r < 4; ++r)
        outbase[r] = (r0 + 4 * lg + r) * (Ss * Hh) + (j0 + ln);

    const int xrowbase = (r0 + ln) * (Ss * Ii);   // A-row = batch r0+ln
    const int hrowoff  = (r0 + ln) * Hh;

    for (int t = 0; t < Ss; ++t) {
        // x fragments (independent of recurrence) — issue before the poll
        short8 xf[8];
#pragma unroll
        for (int ks = 0; ks < 8; ++ks) {
            const float* px = x + xrowbase + t * Ii + 32 * ks + 8 * lg;
            floatx4 a = *(const floatx4*)px;
            floatx4 b = *(const floatx4*)(px + 4);
            short8 v;
#pragma unroll
            for (int q = 0; q < 4; ++q) { v[q] = (short)f2bf(a[q]); v[4 + q] = (short)f2bf(b[q]); }
            xf[ks] = v;
        }

        // wait for all 8 producers to have published h_t
        {
            const unsigned int tgt = (unsigned int)(t + 1);
            unsigned int v;
            do {
                v = __hip_atomic_load(myflag, __ATOMIC_RELAXED, __HIP_MEMORY_SCOPE_AGENT);
            } while (!__all((int)(v >= tgt)));
            __atomic_signal_fence(__ATOMIC_SEQ_CST);  // compiler barrier; HW ordered via MALL
        }

        // h fragments from ring slot (t&1)
        short8 hf[8];
        const unsigned short* rbase = ring + (t & 1) * (Bb * Hh) + hrowoff;
#pragma unroll
        for (int ks = 0; ks < 8; ++ks) {
            unsigned long long* ph = (unsigned long long*)(rbase + 32 * ks + 8 * lg);
            unsigned long long u0 = __hip_atomic_load(ph,     __ATOMIC_RELAXED, __HIP_MEMORY_SCOPE_AGENT);
            unsigned long long u1 = __hip_atomic_load(ph + 1, __ATOMIC_RELAXED, __HIP_MEMORY_SCOPE_AGENT);
            union { unsigned long long u[2]; short8 s; } cv;
            cv.u[0] = u0; cv.u[1] = u1;
            hf[ks] = cv.s;
        }

        floatx4 acc[4];
#pragma unroll
        for (int g = 0; g < 4; ++g) acc[g] = (floatx4){bias[g], bias[g], bias[g], bias[g]};

        // x half first (fragments already in regs; overlaps h-load latency)
#pragma unroll
        for (int ks = 0; ks < 8; ++ks)
#pragma unroll
            for (int g = 0; g < 4; ++g)
                acc[g] = __builtin_amdgcn_mfma_f32_16x16x32_bf16(xf[ks], Bfrag[g][8 + ks], acc[g], 0, 0, 0);
#pragma unroll
        for (int ks = 0; ks < 8; ++ks)
#pragma unroll
            for (int g = 0; g < 4; ++g)
                acc[g] = __builtin_amdgcn_mfma_f32_16x16x32_bf16(hf[ks], Bfrag[g][ks], acc[g], 0, 0, 0);

        // gates + state update, all lane-local
        unsigned short* wslot = ring + ((t + 1) & 1) * (Bb * Hh);
#pragma unroll
        for (int r = 0; r < 4; ++r) {
            float fg = fast_sigmoid(acc[0][r]);
            float ig = fast_sigmoid(acc[1][r]);
            float cd = fast_tanh(acc[2][r]);
            float og = fast_sigmoid(acc[3][r]);
            float c  = cst[r] * fg + ig * cd;
            cst[r] = c;
            float h = og * fast_tanh(c);
            hl[r] = h;
            out[outbase[r] + t * Hh] = h;
            __hip_atomic_store(wslot + (r0 + 4 * lg + r) * Hh + (j0 + ln), f2bf(h),
                               __ATOMIC_RELAXED, __HIP_MEMORY_SCOPE_AGENT);
        }

        __syncthreads();  // all 4 waves' ring stores drained (vmcnt(0) before s_barrier)
        if (tid == 0) {
            __atomic_signal_fence(__ATOMIC_SEQ_CST);
            __hip_atomic_store(flags + wg * 32, (unsigned int)(t + 2),
                               __ATOMIC_RELAXED, __HIP_MEMORY_SCOPE_AGENT);
        }
    }

    // finals: h_f then c_f, each [1,B,H]
    float* hf_out = out + Bb * Ss * Hh;
    float* cf_out = hf_out + Bb * Hh;
#pragma unroll
    for (int r = 0; r < 4; ++r) {
        int b = r0 + 4 * lg + r, j = j0 + ln;
        hf_out[b * Hh + j] = hl[r];
        cf_out[b * Hh + j] = cst[r];
    }
}

extern "C" void kernel_launch(void* const* d_in, const int* in_sizes, int n_in,
                              void* d_out, int out_size, void* d_ws, size_t ws_size,
                              hipStream_t stream) {
    (void)in_sizes; (void)n_in; (void)out_size; (void)ws_size;
    const float* x  = (const float*)d_in[0];
    const float* h0 = (const float*)d_in[1];
    const float* c0 = (const float*)d_in[2];
    const float* Wf = (const float*)d_in[3]; const float* bf = (const float*)d_in[4];
    const float* Wi = (const float*)d_in[5]; const float* bi = (const float*)d_in[6];
    const float* Wc = (const float*)d_in[7]; const float* bc = (const float*)d_in[8];
    const float* Wo = (const float*)d_in[9]; const float* bo = (const float*)d_in[10];

    unsigned int*   flags = (unsigned int*)d_ws;
    unsigned short* ring  = (unsigned short*)((char*)d_ws + 1024);

    // flags must start at 0 (ws is poisoned 0xAA)
    hipMemsetAsync(d_ws, 0, 1024, stream);

    hipLaunchKernelGGL(lstm_persistent, dim3(NWG), dim3(256), 0, stream,
                       x, h0, c0, Wf, bf, Wi, bi, Wc, bc, Wo, bo,
                       (float*)d_out, flags, ring);
}